// Round 9
// baseline (742.491 us; speedup 1.0000x reference)
//
#include <hip/hip_runtime.h>
#include <math.h>

#define D_MODEL 512
#define BATCH 8
#define SEQ 512
#define HEAD 64
#define DK 4
#define DV 8
#define HIDD 10

#define KC 128      // proj k-chunk
#define XPAD 129    // xt row stride (conflict-free lane reads)

// ---------------------------------------------------------------------------
// Projection: [4096 x 512] @ [512 x 1024] -> head-major {Q2|K2|V2}.
// Grid = 64 row-stripes x 16 col-jobs = 1024 blocks (4/CU = 16 waves/CU).
// Lane owns one x-row; wave owns 16 output cols. Per k: 1 ds_read_b32 (x)
// + wave-uniform W float4 loads (-> s_load/SMEM pipe, NOT the LDS pipe)
// feed 16 FMA = 0.25 B/FMA of LDS traffic (R8 was 1.0 -> LDS-BW-bound).
// col-jobs: 0-3 -> Wq, 4-7 -> Wk, 8-15 -> Wv (64 cols each).
// ---------------------------------------------------------------------------
__global__ __launch_bounds__(256) void proj_kernel(
    const float* __restrict__ xq, const float* __restrict__ xkv,
    const float* __restrict__ Wq, const float* __restrict__ Wk,
    const float* __restrict__ Wv,
    float* __restrict__ Q2, float* __restrict__ K2, float* __restrict__ V2)
{
    __shared__ float xt[64 * XPAD];   // 33 KB

    const int t  = threadIdx.x;
    const int cj = blockIdx.x & 15;
    const int br = blockIdx.x >> 4;
    const int r0 = br * 64;

    const float* X; const float* W; int ldw, c0, which;
    if (cj < 4)      { X = xq;  W = Wq; ldw = 256; c0 = cj * 64;       which = 0; }
    else if (cj < 8) { X = xkv; W = Wk; ldw = 256; c0 = (cj - 4) * 64; which = 1; }
    else             { X = xkv; W = Wv; ldw = 512; c0 = (cj - 8) * 64; which = 2; }

    const int lane = t & 63;
    const int wv   = t >> 6;
    const int cw   = c0 + wv * 16;    // this wave's 16 cols (uniform)

    float acc[16];
#pragma unroll
    for (int c = 0; c < 16; ++c) acc[c] = 0.f;

    for (int kc = 0; kc < D_MODEL; kc += KC) {
        __syncthreads();
        // stage x chunk [64 rows][KC]: coalesced b128 global reads,
        // 4x b32 LDS writes (4-way, cheap: 32 wave-ops/chunk)
#pragma unroll
        for (int i = 0; i < 8; ++i) {
            const int slot = t + i * 256;       // 2048 slots = 64 x 32 float4
            const int row  = slot >> 5;
            const int c4   = (slot & 31) * 4;
            const float4 v = *(const float4*)(X + (long)(r0 + row) * D_MODEL + kc + c4);
            xt[row * XPAD + c4 + 0] = v.x;
            xt[row * XPAD + c4 + 1] = v.y;
            xt[row * XPAD + c4 + 2] = v.z;
            xt[row * XPAD + c4 + 3] = v.w;
        }
        __syncthreads();

#pragma unroll 4
        for (int k = 0; k < KC; ++k) {
            const float* wr = W + (long)(kc + k) * ldw + cw;   // uniform addr
            const float4 w0 = *(const float4*)(wr);
            const float4 w1 = *(const float4*)(wr + 4);
            const float4 w2 = *(const float4*)(wr + 8);
            const float4 w3 = *(const float4*)(wr + 12);
            const float xv = xt[lane * XPAD + k];              // 2 lanes/bank = free
            acc[0]  = fmaf(xv, w0.x, acc[0]);  acc[1]  = fmaf(xv, w0.y, acc[1]);
            acc[2]  = fmaf(xv, w0.z, acc[2]);  acc[3]  = fmaf(xv, w0.w, acc[3]);
            acc[4]  = fmaf(xv, w1.x, acc[4]);  acc[5]  = fmaf(xv, w1.y, acc[5]);
            acc[6]  = fmaf(xv, w1.z, acc[6]);  acc[7]  = fmaf(xv, w1.w, acc[7]);
            acc[8]  = fmaf(xv, w2.x, acc[8]);  acc[9]  = fmaf(xv, w2.y, acc[9]);
            acc[10] = fmaf(xv, w2.z, acc[10]); acc[11] = fmaf(xv, w2.w, acc[11]);
            acc[12] = fmaf(xv, w3.x, acc[12]); acc[13] = fmaf(xv, w3.y, acc[13]);
            acc[14] = fmaf(xv, w3.z, acc[14]); acc[15] = fmaf(xv, w3.w, acc[15]);
        }
    }

    // epilogue: head-major scatter; lanes = consecutive s -> coalesced float4
    const int b = r0 >> 9;
    const int s = (r0 & 511) + lane;
    if (which <= 1) {                 // dk=4: 16 cols = 4 heads
        float* dst = (which == 0) ? Q2 : K2;
#pragma unroll
        for (int hh = 0; hh < 4; ++hh) {
            const int h = (cw >> 2) + hh;
            *(float4*)(dst + (((long)b * HEAD + h) * SEQ + s) * 4) =
                make_float4(acc[hh*4+0], acc[hh*4+1], acc[hh*4+2], acc[hh*4+3]);
        }
    } else {                          // dv=8: 16 cols = 2 heads
#pragma unroll
        for (int hh = 0; hh < 2; ++hh) {
            const int h = (cw >> 3) + hh;
            const long vb = (((long)b * HEAD + h) * SEQ + s) * 8;
            *(float4*)(V2 + vb)     = make_float4(acc[hh*8+0], acc[hh*8+1],
                                                  acc[hh*8+2], acc[hh*8+3]);
            *(float4*)(V2 + vb + 4) = make_float4(acc[hh*8+4], acc[hh*8+5],
                                                  acc[hh*8+6], acc[hh*8+7]);
        }
    }
}

// ---------------------------------------------------------------------------
// Attention, ZERO-LDS: K[s]/V[s] are wave-uniform -> scalar/L1-broadcast
// loads (off the LDS pipe that co-bottlenecked R5-R8). 1 query/thread,
// grid = (b,h,q-half) = 1024 blocks x 4 waves = 16 waves/CU, no barriers.
// Online softmax in groups of 8. Causal quirk: masked (s>q) scores are
// EXACTLY 0 and participate in softmax -> full 512-s loop with cndmask.
// ---------------------------------------------------------------------------
template <int CAUSAL>
__global__ __launch_bounds__(256) void attn_kernel(
    const float* __restrict__ Q2, const float* __restrict__ K2,
    const float* __restrict__ V2, float* __restrict__ O)
{
    const int t  = threadIdx.x;
    const int qh = blockIdx.x & 1;
    const int bh = blockIdx.x >> 1;
    const int b  = bh >> 6;
    const int h  = bh & 63;

    const int q = qh * 256 + t;       // wave lanes = consecutive q
    const float4 qv = *(const float4*)(Q2 + ((long)bh * SEQ + q) * 4);
    const float q0 = qv.x * 0.5f, q1 = qv.y * 0.5f;   // fold 1/sqrt(DK)=0.5
    const float q2 = qv.z * 0.5f, q3 = qv.w * 0.5f;

    const float* Kp = K2 + (long)bh * SEQ * DK;
    const float* Vp = V2 + (long)bh * SEQ * DV;

    float m = -INFINITY, l = 0.f;
    float A[8];
#pragma unroll
    for (int d = 0; d < 8; ++d) A[d] = 0.f;

    for (int s0 = 0; s0 < SEQ; s0 += 8) {
        float sc[8];
#pragma unroll
        for (int i = 0; i < 8; ++i) {
            const float4 k4 = *(const float4*)(Kp + (s0 + i) * 4);  // uniform
            float v = fmaf(q0, k4.x, fmaf(q1, k4.y, fmaf(q2, k4.z, q3 * k4.w)));
            if (CAUSAL) v = (s0 + i <= q) ? v : 0.f;   // mult-mask quirk
            sc[i] = v;
        }
        const float gm = fmaxf(fmaxf(fmaxf(sc[0], sc[1]), fmaxf(sc[2], sc[3])),
                               fmaxf(fmaxf(sc[4], sc[5]), fmaxf(sc[6], sc[7])));
        if (gm > m) {
            const float r = __expf(m - gm);
            l *= r;
#pragma unroll
            for (int d = 0; d < 8; ++d) A[d] *= r;
            m = gm;
        }
#pragma unroll
        for (int i = 0; i < 8; ++i) {
            const float p = __expf(sc[i] - m);
            l += p;
            const float4 v0 = *(const float4*)(Vp + (s0 + i) * 8);      // uniform
            const float4 v1 = *(const float4*)(Vp + (s0 + i) * 8 + 4);  // uniform
            A[0] = fmaf(p, v0.x, A[0]); A[1] = fmaf(p, v0.y, A[1]);
            A[2] = fmaf(p, v0.z, A[2]); A[3] = fmaf(p, v0.w, A[3]);
            A[4] = fmaf(p, v1.x, A[4]); A[5] = fmaf(p, v1.y, A[5]);
            A[6] = fmaf(p, v1.z, A[6]); A[7] = fmaf(p, v1.w, A[7]);
        }
    }

    const float inv = 1.0f / l;
    const long ob = ((long)b * SEQ + q) * 512 + h * DV;
    *(float4*)(O + ob)     = make_float4(A[0]*inv, A[1]*inv, A[2]*inv, A[3]*inv);
    *(float4*)(O + ob + 4) = make_float4(A[4]*inv, A[5]*inv, A[6]*inv, A[7]*inv);
}

// ---------------------------------------------------------------------------
// Fused residual + LayerNorm + MLP (512 -> 10 -> 512).
// One WAVE per row; 256 threads = 4 rows/block. (unchanged)
// ---------------------------------------------------------------------------
__global__ __launch_bounds__(256) void ln_mlp_kernel(
    const float* __restrict__ x, const float* __restrict__ fx,
    const float* __restrict__ g, const float* __restrict__ beta,
    const float* __restrict__ w1, const float* __restrict__ b1,
    const float* __restrict__ w2, const float* __restrict__ b2,
    float* __restrict__ out)
{
    const int t = threadIdx.x;
    const int lane = t & 63;
    const int row = blockIdx.x * 4 + (t >> 6);
    const long base = (long)row * D_MODEL;
    const int e0 = lane * 8;

    const float4 xa = *(const float4*)(x + base + e0);
    const float4 xb = *(const float4*)(x + base + e0 + 4);
    const float4 fa = *(const float4*)(fx + base + e0);
    const float4 fb = *(const float4*)(fx + base + e0 + 4);
    float z[8] = {xa.x+fa.x, xa.y+fa.y, xa.z+fa.z, xa.w+fa.w,
                  xb.x+fb.x, xb.y+fb.y, xb.z+fb.z, xb.w+fb.w};

    float sum = 0.f;
#pragma unroll
    for (int j = 0; j < 8; ++j) sum += z[j];
#pragma unroll
    for (int o = 32; o > 0; o >>= 1) sum += __shfl_xor(sum, o);
    float mu = sum * (1.0f / 512.0f);

    float d[8], ss = 0.f;
#pragma unroll
    for (int j = 0; j < 8; ++j) { d[j] = z[j] - mu; ss += d[j] * d[j]; }
#pragma unroll
    for (int o = 32; o > 0; o >>= 1) ss += __shfl_xor(ss, o);
    float rs = rsqrtf(ss * (1.0f / 512.0f) + 1e-5f);

    const float4 ga = *(const float4*)(g + e0);
    const float4 gb = *(const float4*)(g + e0 + 4);
    const float4 ba = *(const float4*)(beta + e0);
    const float4 bb = *(const float4*)(beta + e0 + 4);
    const float gg[8] = {ga.x,ga.y,ga.z,ga.w,gb.x,gb.y,gb.z,gb.w};
    const float bt[8] = {ba.x,ba.y,ba.z,ba.w,bb.x,bb.y,bb.z,bb.w};
    float y[8];
#pragma unroll
    for (int j = 0; j < 8; ++j) y[j] = d[j] * rs * gg[j] + bt[j];

    float part[HIDD];
#pragma unroll
    for (int i = 0; i < HIDD; ++i) {
        const float4 wa = *(const float4*)(w1 + i * 512 + e0);
        const float4 wb = *(const float4*)(w1 + i * 512 + e0 + 4);
        part[i] = y[0]*wa.x + y[1]*wa.y + y[2]*wa.z + y[3]*wa.w
                + y[4]*wb.x + y[5]*wb.y + y[6]*wb.z + y[7]*wb.w;
    }
#pragma unroll
    for (int i = 0; i < HIDD; ++i)
#pragma unroll
        for (int o = 32; o > 0; o >>= 1) part[i] += __shfl_xor(part[i], o);

    float hv[HIDD];
#pragma unroll
    for (int i = 0; i < HIDD; ++i) hv[i] = fmaxf(part[i] + b1[i], 0.f);

    float o8[8];
#pragma unroll
    for (int j = 0; j < 8; ++j) o8[j] = b2[e0 + j];
#pragma unroll
    for (int i = 0; i < HIDD; ++i)
#pragma unroll
        for (int j = 0; j < 8; ++j)
            o8[j] = fmaf(hv[i], w2[(long)(e0 + j) * 10 + i], o8[j]);

    *(float4*)(out + base + e0)     = make_float4(o8[0], o8[1], o8[2], o8[3]);
    *(float4*)(out + base + e0 + 4) = make_float4(o8[4], o8[5], o8[6], o8[7]);
}

extern "C" void kernel_launch(void* const* d_in, const int* in_sizes, int n_in,
                              void* d_out, int out_size, void* d_ws, size_t ws_size,
                              hipStream_t stream) {
    (void)in_sizes; (void)n_in; (void)out_size; (void)ws_size;
    const float* x    = (const float*)d_in[0];
    const float* xenc = (const float*)d_in[1];
    const float* Wq   = (const float*)d_in[2];
    const float* Wk   = (const float*)d_in[3];
    const float* Wv   = (const float*)d_in[4];
    const float* ln_g = (const float*)d_in[5];
    const float* ln_b = (const float*)d_in[6];
    const float* w1   = (const float*)d_in[7];
    const float* b1   = (const float*)d_in[8];
    const float* w2   = (const float*)d_in[9];
    const float* b2   = (const float*)d_in[10];
    float* out = (float*)d_out;

    float* ws = (float*)d_ws;
    float* Q2 = ws;                   // [b][h][s][4]  1,048,576 floats
    float* K2 = Q2 + 1048576;         // [b][h][s][4]  1,048,576 floats
    float* V2 = K2 + 1048576;         // [b][h][s][8]  2,097,152 floats
    float* A  = V2 + 2097152;         // row-major [b][s][512]  2,097,152 floats

    // Stage 1: self-attention (causal multiplicative mask)
    proj_kernel<<<dim3(1024), 256, 0, stream>>>(x, x, Wq, Wk, Wv, Q2, K2, V2);
    attn_kernel<1><<<dim3(BATCH * HEAD * 2), 256, 0, stream>>>(Q2, K2, V2, A);

    // Stage 2: cross-attention (same weights — faithful quirk)
    proj_kernel<<<dim3(1024), 256, 0, stream>>>(A, xenc, Wq, Wk, Wv, Q2, K2, V2);
    attn_kernel<0><<<dim3(BATCH * HEAD * 2), 256, 0, stream>>>(Q2, K2, V2, A);

    // Stage 3: residual(x) + LayerNorm + MLP
    ln_mlp_kernel<<<dim3(BATCH * SEQ / 4), 256, 0, stream>>>(x, A, ln_g, ln_b,
                                                             w1, b1, w2, b2, out);
}

// Round 10
// 357.920 us; speedup vs baseline: 2.0745x; 2.0745x over previous
//
#include <hip/hip_runtime.h>
#include <math.h>

#define D_MODEL 512
#define BATCH 8
#define SEQ 512
#define HEAD 64
#define DK 4
#define DV 8
#define HIDD 10

// proj tiled-GEMM params
#define MR 64    // rows per block
#define KC 32    // k-chunk staged per buffer
#define NC 256   // cols per block

// ---------------------------------------------------------------------------
// Projection as tiled GEMM, k-SPLIT + LDS DOUBLE-BUFFER.
// [4096 x 512] @ [512 x 1024] -> head-major {Q|K|V} partials (sets a/b).
// Grid = 64 row-blocks x 4 col-jobs x 2 k-halves = 512 blocks, 80 KB LDS
// -> 2 blocks/CU = 8 waves/CU. Per chunk: prefetch next chunk into regs
// BEFORE compute, commit to the other buffer after, ONE barrier per chunk
// (R8 had 2 barriers + unhidden VMEM latency = ~50us drain at 38% VALUBusy).
// Per k: 2 W b128 + 2 x b128 (conflict-free) feed 64 FMA.
// ---------------------------------------------------------------------------
__global__ __launch_bounds__(256) void proj_kernel(
    const float* __restrict__ xq, const float* __restrict__ xkv,
    const float* __restrict__ Wq, const float* __restrict__ Wk,
    const float* __restrict__ Wv,
    float* __restrict__ Qa, float* __restrict__ Ka, float* __restrict__ Va,
    float* __restrict__ Qb, float* __restrict__ Kb, float* __restrict__ Vb)
{
    __shared__ float xt[2][KC * MR];   // 2 x  8 KB
    __shared__ float wt[2][KC * NC];   // 2 x 32 KB

    const int t   = threadIdx.x;
    const int bid = blockIdx.x;
    const int ks  = bid & 1;
    const int bj  = (bid >> 1) & 3;
    const int br  = bid >> 3;
    const int r0  = br * MR;
    const int kbase = ks * 256;
    const int kend  = kbase + 256;

    const float* X; const float* W; int ldw; int c0;
    if (bj == 0)      { X = xq;  W = Wq; ldw = 256; c0 = 0;   }
    else if (bj == 1) { X = xkv; W = Wk; ldw = 256; c0 = 0;   }
    else if (bj == 2) { X = xkv; W = Wv; ldw = 512; c0 = 0;   }
    else              { X = xkv; W = Wv; ldw = 512; c0 = 256; }

    float* Q2 = ks ? Qb : Qa;
    float* K2 = ks ? Kb : Ka;
    float* V2 = ks ? Vb : Va;

    const int ct   = t & 31;        // col-thread: cols ct*4 and 128+ct*4
    const int rt   = t >> 5;        // row-thread: rows rt*8..+7
    const int rs   = t & 63;        // x-staging row
    const int kx   = t >> 6;        // x-staging k-octet 0..3
    const int lane = t & 63;        // W-staging lane
    const int wvi  = t >> 6;        // W-staging wave -> rows i*4+wvi

    float4 accL[8], accH[8];
#pragma unroll
    for (int r = 0; r < 8; ++r) {
        accL[r] = make_float4(0.f, 0.f, 0.f, 0.f);
        accH[r] = make_float4(0.f, 0.f, 0.f, 0.f);
    }

    float4 px0, px1, pw[8];
    // preload chunk 0 into regs
    {
        const float* xb = X + (long)(r0 + rs) * D_MODEL + kbase + kx * 8;
        px0 = *(const float4*)(xb);
        px1 = *(const float4*)(xb + 4);
#pragma unroll
        for (int i = 0; i < 8; ++i)
            pw[i] = *(const float4*)(W + (long)(kbase + i * 4 + wvi) * ldw + c0 + lane * 4);
    }
    // commit to buffer 0
    {
        float* xd = xt[0];
        xd[(kx * 8 + 0) * MR + rs] = px0.x; xd[(kx * 8 + 1) * MR + rs] = px0.y;
        xd[(kx * 8 + 2) * MR + rs] = px0.z; xd[(kx * 8 + 3) * MR + rs] = px0.w;
        xd[(kx * 8 + 4) * MR + rs] = px1.x; xd[(kx * 8 + 5) * MR + rs] = px1.y;
        xd[(kx * 8 + 6) * MR + rs] = px1.z; xd[(kx * 8 + 7) * MR + rs] = px1.w;
        float* wd = wt[0];
#pragma unroll
        for (int i = 0; i < 8; ++i)
            *(float4*)(wd + (i * 4 + wvi) * NC + lane * 4) = pw[i];
    }
    __syncthreads();

    int buf = 0;
    for (int kc = kbase; kc < kend; kc += KC) {
        const int kn = kc + KC;
        const bool more = kn < kend;
        if (more) {   // issue next chunk's global loads (land behind compute)
            const float* xb = X + (long)(r0 + rs) * D_MODEL + kn + kx * 8;
            px0 = *(const float4*)(xb);
            px1 = *(const float4*)(xb + 4);
#pragma unroll
            for (int i = 0; i < 8; ++i)
                pw[i] = *(const float4*)(W + (long)(kn + i * 4 + wvi) * ldw + c0 + lane * 4);
        }

        // compute from LDS[buf]: 8x8 split-col register block, 64 FMA per k
        const float* xs = xt[buf];
        const float* wsrc = wt[buf];
#pragma unroll 2
        for (int k = 0; k < KC; ++k) {
            const float4 w0 = *(const float4*)(wsrc + k * NC + ct * 4);
            const float4 w1 = *(const float4*)(wsrc + k * NC + 128 + ct * 4);
            const float4 x0 = *(const float4*)(xs + k * MR + rt * 8);
            const float4 x1 = *(const float4*)(xs + k * MR + rt * 8 + 4);
            const float xr[8] = {x0.x, x0.y, x0.z, x0.w, x1.x, x1.y, x1.z, x1.w};
#pragma unroll
            for (int r = 0; r < 8; ++r) {
                accL[r].x = fmaf(xr[r], w0.x, accL[r].x);
                accL[r].y = fmaf(xr[r], w0.y, accL[r].y);
                accL[r].z = fmaf(xr[r], w0.z, accL[r].z);
                accL[r].w = fmaf(xr[r], w0.w, accL[r].w);
                accH[r].x = fmaf(xr[r], w1.x, accH[r].x);
                accH[r].y = fmaf(xr[r], w1.y, accH[r].y);
                accH[r].z = fmaf(xr[r], w1.z, accH[r].z);
                accH[r].w = fmaf(xr[r], w1.w, accH[r].w);
            }
        }

        if (more) {   // commit prefetched regs to the OTHER buffer
            const int nb = buf ^ 1;
            float* xd = xt[nb];
            xd[(kx * 8 + 0) * MR + rs] = px0.x; xd[(kx * 8 + 1) * MR + rs] = px0.y;
            xd[(kx * 8 + 2) * MR + rs] = px0.z; xd[(kx * 8 + 3) * MR + rs] = px0.w;
            xd[(kx * 8 + 4) * MR + rs] = px1.x; xd[(kx * 8 + 5) * MR + rs] = px1.y;
            xd[(kx * 8 + 6) * MR + rs] = px1.z; xd[(kx * 8 + 7) * MR + rs] = px1.w;
            float* wd = wt[nb];
#pragma unroll
            for (int i = 0; i < 8; ++i)
                *(float4*)(wd + (i * 4 + wvi) * NC + lane * 4) = pw[i];
            __syncthreads();
            buf = nb;
        }
    }

    // ---- epilogue: head-major scatter ----
    const int b  = r0 >> 9;
    const int sb = (r0 & 511) + rt * 8;
    if (bj <= 1) {
        float* dst = (bj == 0) ? Q2 : K2;
        const long hlo = ((long)b * HEAD + ct) * SEQ;
        const long hhi = ((long)b * HEAD + 32 + ct) * SEQ;
#pragma unroll
        for (int r = 0; r < 8; ++r) {
            *(float4*)(dst + (hlo + sb + r) * 4) = accL[r];
            *(float4*)(dst + (hhi + sb + r) * 4) = accH[r];
        }
    } else {
        const int clo = c0 + ct * 4;
        const int chi = clo + 128;
        const long vlo = ((long)b * HEAD + (clo >> 3)) * SEQ;
        const long vhi = ((long)b * HEAD + (chi >> 3)) * SEQ;
        const int off = (ct & 1) * 4;
#pragma unroll
        for (int r = 0; r < 8; ++r) {
            *(float4*)(V2 + (vlo + sb + r) * 8 + off) = accL[r];
            *(float4*)(V2 + (vhi + sb + r) * 8 + off) = accH[r];
        }
    }
}

// ---------------------------------------------------------------------------
// Attention: one block per (b,h); 256 threads; 2 queries/thread (q=2t,2t+1).
// Grid 512 x 4 waves = 8 waves/CU; each K/V LDS b128 serves 2 queries.
// K/V/Q inputs are two k-split partials, summed during staging (ADD2).
// Causal quirk: masked (s>q) scores are exactly 0 and participate; remainder
// predicates q0; s>q1 handled as lump exp(-M)*(count, suffixSumV).
// ---------------------------------------------------------------------------
template <int CAUSAL>
__global__ __launch_bounds__(256) void attn_kernel(
    const float* __restrict__ Qa, const float* __restrict__ Ka,
    const float* __restrict__ Va, const float* __restrict__ Qb,
    const float* __restrict__ Kb, const float* __restrict__ Vb,
    float* __restrict__ O)
{
    extern __shared__ float smem[];
    float* Kl = smem;                 // SEQ*DK = 2048 floats
    float* Vl = smem + SEQ * DK;      // SEQ*DV = 4096 floats
    float* cs = Vl + SEQ * DV;        // 33*DV  =  264 floats (causal only)

    const int t  = threadIdx.x;
    const int bh = blockIdx.x;
    const int b  = bh >> 6;
    const int h  = bh & 63;

    const float4* Ksa = (const float4*)(Ka + (long)bh * SEQ * DK);
    const float4* Ksb = (const float4*)(Kb + (long)bh * SEQ * DK);
#pragma unroll
    for (int i = 0; i < 2; ++i) {
        float4 v = Ksa[t + i * 256];
        const float4 w = Ksb[t + i * 256];
        v.x += w.x; v.y += w.y; v.z += w.z; v.w += w.w;
        ((float4*)Kl)[t + i * 256] = v;
    }
    const float4* Vsa = (const float4*)(Va + (long)bh * SEQ * DV);
    const float4* Vsb = (const float4*)(Vb + (long)bh * SEQ * DV);
#pragma unroll
    for (int i = 0; i < 4; ++i) {
        float4 v = Vsa[t + i * 256];
        const float4 w = Vsb[t + i * 256];
        v.x += w.x; v.y += w.y; v.z += w.z; v.w += w.w;
        ((float4*)Vl)[t + i * 256] = v;
    }
    __syncthreads();

    if (CAUSAL) {
        const int ch = t >> 3, d = t & 7;
        float s16 = 0.f;
#pragma unroll
        for (int i = 0; i < 16; ++i) s16 += Vl[(ch * 16 + i) * 8 + d];
        cs[ch * 8 + d] = s16;
        __syncthreads();
        if (t < 8) {
            cs[256 + t] = 0.f;
            float run = 0.f;
            for (int c2 = 31; c2 >= 0; --c2) {
                run += cs[c2 * 8 + t];
                cs[c2 * 8 + t] = run;   // inclusive suffix of chunk c2
            }
        }
        __syncthreads();
    }

    const int q0 = 2 * t, q1 = q0 + 1;
    float4 qva = *(const float4*)(Qa + ((long)bh * SEQ + q0) * 4);
    float4 qvb = *(const float4*)(Qa + ((long)bh * SEQ + q1) * 4);
    {
        const float4 wa = *(const float4*)(Qb + ((long)bh * SEQ + q0) * 4);
        const float4 wb = *(const float4*)(Qb + ((long)bh * SEQ + q1) * 4);
        qva.x += wa.x; qva.y += wa.y; qva.z += wa.z; qva.w += wa.w;
        qvb.x += wb.x; qvb.y += wb.y; qvb.z += wb.z; qvb.w += wb.w;
    }
    const float qa0 = qva.x*0.5f, qa1 = qva.y*0.5f, qa2 = qva.z*0.5f, qa3 = qva.w*0.5f;
    const float qb0 = qvb.x*0.5f, qb1 = qvb.y*0.5f, qb2 = qvb.z*0.5f, qb3 = qvb.w*0.5f;

    float m0 = -INFINITY, l0 = 0.f, m1 = -INFINITY, l1 = 0.f;
    float A0[8], A1[8];
#pragma unroll
    for (int d = 0; d < 8; ++d) { A0[d] = 0.f; A1[d] = 0.f; }

    const int full_end = CAUSAL ? (q0 + 1) : SEQ;

    int s0 = 0;
    for (; s0 + 8 <= full_end; s0 += 8) {
        float sa[8], sb[8];
#pragma unroll
        for (int i = 0; i < 8; ++i) {
            const float4 k4 = *(const float4*)(Kl + (s0 + i) * 4);
            sa[i] = fmaf(qa0, k4.x, fmaf(qa1, k4.y, fmaf(qa2, k4.z, qa3 * k4.w)));
            sb[i] = fmaf(qb0, k4.x, fmaf(qb1, k4.y, fmaf(qb2, k4.z, qb3 * k4.w)));
        }
        const float ga = fmaxf(fmaxf(fmaxf(sa[0], sa[1]), fmaxf(sa[2], sa[3])),
                               fmaxf(fmaxf(sa[4], sa[5]), fmaxf(sa[6], sa[7])));
        const float gb = fmaxf(fmaxf(fmaxf(sb[0], sb[1]), fmaxf(sb[2], sb[3])),
                               fmaxf(fmaxf(sb[4], sb[5]), fmaxf(sb[6], sb[7])));
        if (ga > m0) {
            const float r = __expf(m0 - ga);
            l0 *= r;
#pragma unroll
            for (int d = 0; d < 8; ++d) A0[d] *= r;
            m0 = ga;
        }
        if (gb > m1) {
            const float r = __expf(m1 - gb);
            l1 *= r;
#pragma unroll
            for (int d = 0; d < 8; ++d) A1[d] *= r;
            m1 = gb;
        }
#pragma unroll
        for (int i = 0; i < 8; ++i) {
            const float p0 = __expf(sa[i] - m0);
            const float p1 = __expf(sb[i] - m1);
            l0 += p0; l1 += p1;
            const float4 v0 = *(const float4*)(Vl + (s0 + i) * 8);
            const float4 v1 = *(const float4*)(Vl + (s0 + i) * 8 + 4);
            A0[0] = fmaf(p0, v0.x, A0[0]); A0[1] = fmaf(p0, v0.y, A0[1]);
            A0[2] = fmaf(p0, v0.z, A0[2]); A0[3] = fmaf(p0, v0.w, A0[3]);
            A0[4] = fmaf(p0, v1.x, A0[4]); A0[5] = fmaf(p0, v1.y, A0[5]);
            A0[6] = fmaf(p0, v1.z, A0[6]); A0[7] = fmaf(p0, v1.w, A0[7]);
            A1[0] = fmaf(p1, v0.x, A1[0]); A1[1] = fmaf(p1, v0.y, A1[1]);
            A1[2] = fmaf(p1, v0.z, A1[2]); A1[3] = fmaf(p1, v0.w, A1[3]);
            A1[4] = fmaf(p1, v1.x, A1[4]); A1[5] = fmaf(p1, v1.y, A1[5]);
            A1[6] = fmaf(p1, v1.z, A1[6]); A1[7] = fmaf(p1, v1.w, A1[7]);
        }
    }

    if (CAUSAL) {
        for (int s = s0; s <= q1; ++s) {        // remainder: covers s=q0+1
            const float4 k4 = *(const float4*)(Kl + s * 4);
            float sa = fmaf(qa0, k4.x, fmaf(qa1, k4.y, fmaf(qa2, k4.z, qa3 * k4.w)));
            float sb = fmaf(qb0, k4.x, fmaf(qb1, k4.y, fmaf(qb2, k4.z, qb3 * k4.w)));
            sa = (s <= q0) ? sa : 0.f;          // mult-mask quirk: exact 0
            if (sa > m0) {
                const float r = __expf(m0 - sa);
                l0 *= r;
#pragma unroll
                for (int d = 0; d < 8; ++d) A0[d] *= r;
                m0 = sa;
            }
            if (sb > m1) {
                const float r = __expf(m1 - sb);
                l1 *= r;
#pragma unroll
                for (int d = 0; d < 8; ++d) A1[d] *= r;
                m1 = sb;
            }
            const float p0 = __expf(sa - m0);
            const float p1 = __expf(sb - m1);
            l0 += p0; l1 += p1;
            const float4 v0 = *(const float4*)(Vl + s * 8);
            const float4 v1 = *(const float4*)(Vl + s * 8 + 4);
            A0[0] = fmaf(p0, v0.x, A0[0]); A0[1] = fmaf(p0, v0.y, A0[1]);
            A0[2] = fmaf(p0, v0.z, A0[2]); A0[3] = fmaf(p0, v0.w, A0[3]);
            A0[4] = fmaf(p0, v1.x, A0[4]); A0[5] = fmaf(p0, v1.y, A0[5]);
            A0[6] = fmaf(p0, v1.z, A0[6]); A0[7] = fmaf(p0, v1.w, A0[7]);
            A1[0] = fmaf(p1, v0.x, A1[0]); A1[1] = fmaf(p1, v0.y, A1[1]);
            A1[2] = fmaf(p1, v0.z, A1[2]); A1[3] = fmaf(p1, v0.w, A1[3]);
            A1[4] = fmaf(p1, v1.x, A1[4]); A1[5] = fmaf(p1, v1.y, A1[5]);
            A1[6] = fmaf(p1, v1.z, A1[6]); A1[7] = fmaf(p1, v1.w, A1[7]);
        }

        const int n = SEQ - 1 - q1;             // masked zeros beyond q1
        if (n > 0) {
            const int nq  = q1 + 1;
            const int cq2 = nq >> 4;
            float sv[8];
#pragma unroll
            for (int d = 0; d < 8; ++d) sv[d] = cs[(cq2 + 1) * 8 + d];
            for (int s = nq; s < (cq2 + 1) * 16; ++s) {
                const float4 v0 = *(const float4*)(Vl + s * 8);
                const float4 v1 = *(const float4*)(Vl + s * 8 + 4);
                sv[0] += v0.x; sv[1] += v0.y; sv[2] += v0.z; sv[3] += v0.w;
                sv[4] += v1.x; sv[5] += v1.y; sv[6] += v1.z; sv[7] += v1.w;
            }
            const float pm0 = __expf(-m0);      // m0 >= 0 (saw in-loop zero)
            l0 += pm0 * (float)n;
#pragma unroll
            for (int d = 0; d < 8; ++d) A0[d] = fmaf(pm0, sv[d], A0[d]);

            const float M1  = fmaxf(m1, 0.f);
            const float r1  = __expf(m1 - M1);
            const float pm1 = __expf(-M1);
            l1 = l1 * r1 + pm1 * (float)n;
#pragma unroll
            for (int d = 0; d < 8; ++d) A1[d] = A1[d] * r1 + pm1 * sv[d];
        }
    }

    const float i0 = 1.0f / l0, i1 = 1.0f / l1;
    const long ob0 = ((long)b * SEQ + q0) * 512 + h * DV;
    const long ob1 = ((long)b * SEQ + q1) * 512 + h * DV;
    *(float4*)(O + ob0)     = make_float4(A0[0]*i0, A0[1]*i0, A0[2]*i0, A0[3]*i0);
    *(float4*)(O + ob0 + 4) = make_float4(A0[4]*i0, A0[5]*i0, A0[6]*i0, A0[7]*i0);
    *(float4*)(O + ob1)     = make_float4(A1[0]*i1, A1[1]*i1, A1[2]*i1, A1[3]*i1);
    *(float4*)(O + ob1 + 4) = make_float4(A1[4]*i1, A1[5]*i1, A1[6]*i1, A1[7]*i1);
}

// ---------------------------------------------------------------------------
// Fused residual + LayerNorm + MLP (512 -> 10 -> 512).
// One WAVE per row; 256 threads = 4 rows/block. (unchanged)
// ---------------------------------------------------------------------------
__global__ __launch_bounds__(256) void ln_mlp_kernel(
    const float* __restrict__ x, const float* __restrict__ fx,
    const float* __restrict__ g, const float* __restrict__ beta,
    const float* __restrict__ w1, const float* __restrict__ b1,
    const float* __restrict__ w2, const float* __restrict__ b2,
    float* __restrict__ out)
{
    const int t = threadIdx.x;
    const int lane = t & 63;
    const int row = blockIdx.x * 4 + (t >> 6);
    const long base = (long)row * D_MODEL;
    const int e0 = lane * 8;

    const float4 xa = *(const float4*)(x + base + e0);
    const float4 xb = *(const float4*)(x + base + e0 + 4);
    const float4 fa = *(const float4*)(fx + base + e0);
    const float4 fb = *(const float4*)(fx + base + e0 + 4);
    float z[8] = {xa.x+fa.x, xa.y+fa.y, xa.z+fa.z, xa.w+fa.w,
                  xb.x+fb.x, xb.y+fb.y, xb.z+fb.z, xb.w+fb.w};

    float sum = 0.f;
#pragma unroll
    for (int j = 0; j < 8; ++j) sum += z[j];
#pragma unroll
    for (int o = 32; o > 0; o >>= 1) sum += __shfl_xor(sum, o);
    float mu = sum * (1.0f / 512.0f);

    float d[8], ss = 0.f;
#pragma unroll
    for (int j = 0; j < 8; ++j) { d[j] = z[j] - mu; ss += d[j] * d[j]; }
#pragma unroll
    for (int o = 32; o > 0; o >>= 1) ss += __shfl_xor(ss, o);
    float rs = rsqrtf(ss * (1.0f / 512.0f) + 1e-5f);

    const float4 ga = *(const float4*)(g + e0);
    const float4 gb = *(const float4*)(g + e0 + 4);
    const float4 ba = *(const float4*)(beta + e0);
    const float4 bb = *(const float4*)(beta + e0 + 4);
    const float gg[8] = {ga.x,ga.y,ga.z,ga.w,gb.x,gb.y,gb.z,gb.w};
    const float bt[8] = {ba.x,ba.y,ba.z,ba.w,bb.x,bb.y,bb.z,bb.w};
    float y[8];
#pragma unroll
    for (int j = 0; j < 8; ++j) y[j] = d[j] * rs * gg[j] + bt[j];

    float part[HIDD];
#pragma unroll
    for (int i = 0; i < HIDD; ++i) {
        const float4 wa = *(const float4*)(w1 + i * 512 + e0);
        const float4 wb = *(const float4*)(w1 + i * 512 + e0 + 4);
        part[i] = y[0]*wa.x + y[1]*wa.y + y[2]*wa.z + y[3]*wa.w
                + y[4]*wb.x + y[5]*wb.y + y[6]*wb.z + y[7]*wb.w;
    }
#pragma unroll
    for (int i = 0; i < HIDD; ++i)
#pragma unroll
        for (int o = 32; o > 0; o >>= 1) part[i] += __shfl_xor(part[i], o);

    float hv[HIDD];
#pragma unroll
    for (int i = 0; i < HIDD; ++i) hv[i] = fmaxf(part[i] + b1[i], 0.f);

    float o8[8];
#pragma unroll
    for (int j = 0; j < 8; ++j) o8[j] = b2[e0 + j];
#pragma unroll
    for (int i = 0; i < HIDD; ++i)
#pragma unroll
        for (int j = 0; j < 8; ++j)
            o8[j] = fmaf(hv[i], w2[(long)(e0 + j) * 10 + i], o8[j]);

    *(float4*)(out + base + e0)     = make_float4(o8[0], o8[1], o8[2], o8[3]);
    *(float4*)(out + base + e0 + 4) = make_float4(o8[4], o8[5], o8[6], o8[7]);
}

extern "C" void kernel_launch(void* const* d_in, const int* in_sizes, int n_in,
                              void* d_out, int out_size, void* d_ws, size_t ws_size,
                              hipStream_t stream) {
    (void)in_sizes; (void)n_in; (void)out_size; (void)ws_size;
    const float* x    = (const float*)d_in[0];
    const float* xenc = (const float*)d_in[1];
    const float* Wq   = (const float*)d_in[2];
    const float* Wk   = (const float*)d_in[3];
    const float* Wv   = (const float*)d_in[4];
    const float* ln_g = (const float*)d_in[5];
    const float* ln_b = (const float*)d_in[6];
    const float* w1   = (const float*)d_in[7];
    const float* b1   = (const float*)d_in[8];
    const float* w2   = (const float*)d_in[9];
    const float* b2   = (const float*)d_in[10];
    float* out = (float*)d_out;

    float* ws = (float*)d_ws;
    float* Qa = ws;
    float* Ka = Qa + 1048576;
    float* Va = Ka + 1048576;
    float* Qb = Va + 2097152;
    float* Kb = Qb + 1048576;
    float* Vb = Kb + 1048576;
    float* A  = Vb + 2097152;

    const size_t lds_cross  = (size_t)(SEQ * DK + SEQ * DV) * 4;          // 24576
    const size_t lds_causal = lds_cross + (size_t)(33 * DV) * 4;          // 25632

    // Stage 1: self-attention (causal multiplicative mask)
    proj_kernel<<<dim3(512), 256, 0, stream>>>(x, x, Wq, Wk, Wv,
                                               Qa, Ka, Va, Qb, Kb, Vb);
    attn_kernel<1><<<dim3(BATCH * HEAD), 256, lds_causal, stream>>>(
        Qa, Ka, Va, Qb, Kb, Vb, A);

    // Stage 2: cross-attention (same weights — faithful quirk)
    proj_kernel<<<dim3(512), 256, 0, stream>>>(A, xenc, Wq, Wk, Wv,
                                               Qa, Ka, Va, Qb, Kb, Vb);
    attn_kernel<0><<<dim3(BATCH * HEAD), 256, lds_cross, stream>>>(
        Qa, Ka, Va, Qb, Kb, Vb, A);

    // Stage 3: residual(x) + LayerNorm + MLP
    ln_mlp_kernel<<<dim3(BATCH * SEQ / 4), 256, 0, stream>>>(x, A, ln_g, ln_b,
                                                             w1, b1, w2, b2, out);
}